// Round 14
// baseline (374.036 us; speedup 1.0000x reference)
//
#include <hip/hip_runtime.h>
#include <stdint.h>

// ---------------- problem constants ----------------
#define NBI 4
#define RRI 512
#define NROI 2048
#define DIN 12544      // 256*7*7
#define BBOX_CLIP_F 4.135166556742356f

typedef _Float16 half8 __attribute__((ext_vector_type(8)));
typedef float f32x16 __attribute__((ext_vector_type(16)));

// ---------------- workspace layout (bytes) ----------------
#define O_AH      10240000ull
#define O_AL      61620224ull
#define O_WTH     113000448ull
#define O_WTL     138690560ull
#define OZ        164380672ull
#define WS_NEED   189546496ull

#define O_X2H     0ull
#define O_X2L     2097152ull
#define O_X1H     O_AH
#define O_X1L     (O_AH + 4194304ull)
#define O_PBOX    O_AL
#define O_KEYS    (O_AL + 2949120ull)
#define O_NMSBOX  (O_AL + 3473408ull)
#define O_OUTBOX  (O_AL + 3604480ull)
#define O_SCORE   (O_AL + 3735552ull)
#define O_LABEL   (O_AL + 3768320ull)
#define O_CNT     (O_AL + 3801088ull)
#define O_MASK    (O_AL + 3802112ull)
#define O_WHH     O_WTH
#define O_WHL     (O_WTH + 1048576ull)
#define O_BH      (O_WTH + 2097152ull)
#define O_PARTH   (O_WTH + 2101248ull)          // 16.8MB: heads partials; FC2 P2 slice
#define O_W2TH    (O_WTH + 18878464ull)         // W2 splits live in WTH region (post-FC1)
#define O_W2TL    (O_WTH + 20975616ull)

// ---------------- features transpose + d_out zero (fused) ----------------
__global__ __launch_bounds__(256) void k_transpose(const float* __restrict__ f,
                                                   float* __restrict__ ft,
                                                   float* __restrict__ out) {
  __shared__ float s[32][33];
  int b = blockIdx.z;
  int hw0 = blockIdx.x << 5;
  int c0 = blockIdx.y << 5;
  if (blockIdx.y == 0 && blockIdx.z == 0 && blockIdx.x < 10) {
    int i = blockIdx.x * 256 + threadIdx.x;
    if (i < 2400) out[i] = 0.0f;
  }
  int tx = threadIdx.x & 31, ty = threadIdx.x >> 5;
#pragma unroll
  for (int j = 0; j < 32; j += 8) {
    int hw = hw0 + tx;
    if (hw < 2500) s[ty + j][tx] = f[((size_t)b * 256 + c0 + ty + j) * 2500 + hw];
  }
  __syncthreads();
#pragma unroll
  for (int j = 0; j < 32; j += 8) {
    int hw = hw0 + ty + j;
    if (hw < 2500) ft[((size_t)b * 2500 + hw) * 256 + c0 + tx] = s[tx][ty + j];
  }
}

// ---------------- W [K][N] f32 -> transposed split Th/Tl [N][K] fp16 ----------------
__global__ __launch_bounds__(256) void k_wsplit(const float* __restrict__ W,
                                                _Float16* __restrict__ Th,
                                                _Float16* __restrict__ Tl, int K, int N) {
  __shared__ float s[64][68];
  int k0 = blockIdx.x << 6, n0 = blockIdx.y << 6;
  int t = threadIdx.x;
  int r = t >> 2, c4 = (t & 3) << 4;
#pragma unroll
  for (int j = 0; j < 16; j += 4) {
    float4 v = *(const float4*)(W + (size_t)(k0 + r) * N + n0 + c4 + j);
    s[r][c4 + j] = v.x; s[r][c4 + j + 1] = v.y; s[r][c4 + j + 2] = v.z; s[r][c4 + j + 3] = v.w;
  }
  __syncthreads();
  int nr = t >> 2, kc = (t & 3) << 4;
  half8 h8[2], l8[2];
#pragma unroll
  for (int j = 0; j < 16; ++j) {
    float v = s[kc + j][nr];
    _Float16 h = (_Float16)v;
    _Float16 lo = (_Float16)((v - (float)h) * 2048.0f);
    h8[j >> 3][j & 7] = h;
    l8[j >> 3][j & 7] = lo;
  }
  size_t base = (size_t)(n0 + nr) * K + k0 + kc;
  *(half8*)(Th + base) = h8[0]; *(half8*)(Th + base + 8) = h8[1];
  *(half8*)(Tl + base) = l8[0]; *(half8*)(Tl + base + 8) = l8[1];
}

// ---------------- fused prep: W2 split (blocks 0..255) + heads split + key/cnt zero ----
__global__ __launch_bounds__(256) void k_prep2(const float* __restrict__ W2,
                                               const float* __restrict__ Wc,
                                               const float* __restrict__ Wr,
                                               const float* __restrict__ bcv,
                                               const float* __restrict__ brv,
                                               _Float16* __restrict__ T2h,
                                               _Float16* __restrict__ T2l,
                                               _Float16* __restrict__ Th,
                                               _Float16* __restrict__ Tl,
                                               float* __restrict__ bh,
                                               unsigned* __restrict__ keys32,
                                               unsigned* __restrict__ cnt) {
  int blk = blockIdx.x;
  int t = threadIdx.x;
  if (blk < 256) {   // W2 [1024][1024] transpose-split, tile (k0,n0)
    __shared__ float s[64][68];
    int k0 = (blk & 15) << 6, n0 = (blk >> 4) << 6;
    int r = t >> 2, c4 = (t & 3) << 4;
#pragma unroll
    for (int j = 0; j < 16; j += 4) {
      float4 v = *(const float4*)(W2 + (size_t)(k0 + r) * 1024 + n0 + c4 + j);
      s[r][c4 + j] = v.x; s[r][c4 + j + 1] = v.y; s[r][c4 + j + 2] = v.z; s[r][c4 + j + 3] = v.w;
    }
    __syncthreads();
    int nr = t >> 2, kc = (t & 3) << 4;
    half8 h8[2], l8[2];
#pragma unroll
    for (int j = 0; j < 16; ++j) {
      float v = s[kc + j][nr];
      _Float16 h = (_Float16)v;
      _Float16 lo = (_Float16)((v - (float)h) * 2048.0f);
      h8[j >> 3][j & 7] = h;
      l8[j >> 3][j & 7] = lo;
    }
    size_t base = (size_t)(n0 + nr) * 1024 + k0 + kc;
    *(half8*)(T2h + base) = h8[0]; *(half8*)(T2h + base + 8) = h8[1];
    *(half8*)(T2l + base) = l8[0]; *(half8*)(T2l + base + 8) = l8[1];
  } else {           // heads weights row n + zero keys/cnt
    int n = blk - 256;          // 0..511
    keys32[(n << 8) + t] = 0u;
    if (n == 0 && t < 64) cnt[t] = 0u;
    for (int k = t; k < 1024; k += 256) {
      float v = (n < 91) ? Wc[(size_t)k * 91 + n]
                         : ((n < 455) ? Wr[(size_t)k * 364 + (n - 91)] : 0.0f);
      _Float16 h = (_Float16)v;
      Th[(size_t)n * 1024 + k] = h;
      Tl[(size_t)n * 1024 + k] = (_Float16)((v - (float)h) * 2048.0f);
    }
    if (t == 0) bh[n] = (n < 91) ? bcv[n] : ((n < 455) ? brv[n - 91] : 0.0f);
  }
}

// ---------------- RoI align -> Ah/Al fp16 split [2048][12544] ----------------
__global__ __launch_bounds__(256) void k_roialign(const float* __restrict__ ft,
                                                  const float* __restrict__ props,
                                                  _Float16* __restrict__ Ahg,
                                                  _Float16* __restrict__ Alg) {
  __shared__ float pool[DIN];
  __shared__ float lyA[7], lxA[7];
  __shared__ int y0A[7], y1A[7], x0A[7], x1A[7];
  int roi = blockIdx.x;
  int b = roi >> 9;
  const float* p = props + (size_t)roi * 4;
  float x1s = p[0] * 0.0625f, y1s = p[1] * 0.0625f;
  float x2s = p[2] * 0.0625f, y2s = p[3] * 0.0625f;
  float bh = (y2s - y1s) / 7.0f;
  float bw = (x2s - x1s) / 7.0f;
  int t = threadIdx.x;
  if (t < 7) {
    float y = y1s + ((float)t + 0.5f) * bh;
    y = fminf(fmaxf(y, 0.0f), 49.0f);
    float y0 = floorf(y);
    int y0i = (int)y0;
    y0A[t] = y0i; y1A[t] = min(y0i + 1, 49); lyA[t] = y - y0;
  } else if (t < 14) {
    int px = t - 7;
    float x = x1s + ((float)px + 0.5f) * bw;
    x = fminf(fmaxf(x, 0.0f), 49.0f);
    float x0 = floorf(x);
    int x0i = (int)x0;
    x0A[px] = x0i; x1A[px] = min(x0i + 1, 49); lxA[px] = x - x0;
  }
  __syncthreads();
  const float* fb = ft + (size_t)b * 2500 * 256;
  int c = t;
  for (int p49 = 0; p49 < 49; ++p49) {
    int py = p49 / 7, px = p49 - py * 7;
    int y0 = y0A[py], y1 = y1A[py], x0 = x0A[px], x1 = x1A[px];
    float ly = lyA[py], lx = lxA[px], hy = 1.0f - ly, hx = 1.0f - lx;
    float f00 = fb[(y0 * 50 + x0) * 256 + c];
    float f01 = fb[(y0 * 50 + x1) * 256 + c];
    float f10 = fb[(y1 * 50 + x0) * 256 + c];
    float f11 = fb[(y1 * 50 + x1) * 256 + c];
    pool[c * 49 + p49] = (hy * hx) * f00 + (hy * lx) * f01 + (ly * hx) * f10 + (ly * lx) * f11;
  }
  __syncthreads();
  _Float16* dh = Ahg + (size_t)roi * DIN;
  _Float16* dl = Alg + (size_t)roi * DIN;
  for (int i8 = t; i8 < 1568; i8 += 256) {   // 1568*8 = 12544, vectorized stores
    half8 h8v, l8v;
#pragma unroll
    for (int j = 0; j < 8; ++j) {
      float v = pool[i8 * 8 + j];
      _Float16 h = (_Float16)v;
      h8v[j] = h;
      l8v[j] = (_Float16)((v - (float)h) * 2048.0f);
    }
    *(half8*)(dh + (size_t)i8 * 8) = h8v;
    *(half8*)(dl + (size_t)i8 * 8) = l8v;
  }
}

// ---------------- MFMA GEMM: 32x32x16 f16, hi/lo 3-term, BM=BN=128, BK=32 -------------
// R11-proven core: 256 threads = 4 waves (2x2); wave tile 64x64.  Both operands staged
// via registers into FRAGMENT-MAJOR LDS (slot ((r>>5)*4+c)*32+(r&31)): staging writes
// and fragment reads are contiguous per 32-lane group => conflict-free.  Double-buffered,
// ONE barrier per K-step; global loads issued 2 tiles ahead.  T1 chunked XCD swizzle.
__global__ __launch_bounds__(256, 2) void k_mfma(const _Float16* __restrict__ Ah,
                                                 const _Float16* __restrict__ Al,
                                                 const _Float16* __restrict__ Bh,
                                                 const _Float16* __restrict__ Bl,
                                                 float* __restrict__ P0,
                                                 float* __restrict__ P2,
                                                 int K, int K2, int ldc, int MN) {
  __shared__ __align__(16) half8 sA[2][2][512];   // [buf][hi/lo][slot]
  __shared__ __align__(16) half8 sB[2][2][512];
  int gx = gridDim.x, gy = gridDim.y;
  int nwg = gx * gy * gridDim.z;
  int lin = blockIdx.x + gx * (blockIdx.y + gy * blockIdx.z);
  int cpx = nwg >> 3;                     // all grids are multiples of 8
  int nl = (lin & 7) * cpx + (lin >> 3);  // bijective chunked T1 remap
  int sx = __ffs(gx) - 1, sy = __ffs(gy) - 1;
  int lx = nl & (gx - 1);
  int rest = nl >> sx;
  int ly = rest & (gy - 1);
  int lz = rest >> sy;
  int m0 = ly << 7, n0 = lx << 7;
  int kb = lz * K2;
  int t = threadIdx.x;
  int w = t >> 6, l = t & 63;
  int wr = w >> 1, wc = w & 1;
  int fr = l & 31, cgrp = l >> 5;
  // staging: thread stages row sr, chunks {2*sh, 2*sh+1} (32B) per array
  int sr = t >> 1, sh = t & 1;
  const _Float16* gAh = Ah + (size_t)(m0 + sr) * K + kb + sh * 16;
  const _Float16* gAl = Al + (size_t)(m0 + sr) * K + kb + sh * 16;
  const _Float16* gBh = Bh + (size_t)(n0 + sr) * K + kb + sh * 16;
  const _Float16* gBl = Bl + (size_t)(n0 + sr) * K + kb + sh * 16;
  int ws0 = ((sr >> 5) * 4 + 2 * sh) * 32 + (sr & 31);  // fragment-major dest slots
  int ws1 = ws0 + 32;
  // fragment read slot bases: slot(mf,s) = base + mf*128 + s*64
  int sa0 = wr * 256 + cgrp * 32 + fr;
  int sb0 = wc * 256 + cgrp * 32 + fr;
  f32x16 accH[2][2], accL[2][2];
#pragma unroll
  for (int i = 0; i < 2; ++i)
#pragma unroll
    for (int j = 0; j < 2; ++j)
#pragma unroll
      for (int r = 0; r < 16; ++r) { accH[i][j][r] = 0.0f; accL[i][j][r] = 0.0f; }
  // prologue: tile0 -> buf0; prefetch tile1 into regs
  half8 rAh0 = *(const half8*)gAh, rAh1 = *(const half8*)(gAh + 8);
  half8 rAl0 = *(const half8*)gAl, rAl1 = *(const half8*)(gAl + 8);
  half8 rBh0 = *(const half8*)gBh, rBh1 = *(const half8*)(gBh + 8);
  half8 rBl0 = *(const half8*)gBl, rBl1 = *(const half8*)(gBl + 8);
  sA[0][0][ws0] = rAh0; sA[0][0][ws1] = rAh1;
  sA[0][1][ws0] = rAl0; sA[0][1][ws1] = rAl1;
  sB[0][0][ws0] = rBh0; sB[0][0][ws1] = rBh1;
  sB[0][1][ws0] = rBl0; sB[0][1][ws1] = rBl1;
  if (32 < K2) {
    rAh0 = *(const half8*)(gAh + 32); rAh1 = *(const half8*)(gAh + 40);
    rAl0 = *(const half8*)(gAl + 32); rAl1 = *(const half8*)(gAl + 40);
    rBh0 = *(const half8*)(gBh + 32); rBh1 = *(const half8*)(gBh + 40);
    rBl0 = *(const half8*)(gBl + 32); rBl1 = *(const half8*)(gBl + 40);
  }
  __syncthreads();
  for (int kt = 0; kt < K2; kt += 32) {
    int buf = (kt >> 5) & 1;
    bool more = (kt + 32) < K2;
    if (more) {                      // write tile kt+32 (in regs) into buf^1
      sA[buf ^ 1][0][ws0] = rAh0; sA[buf ^ 1][0][ws1] = rAh1;
      sA[buf ^ 1][1][ws0] = rAl0; sA[buf ^ 1][1][ws1] = rAl1;
      sB[buf ^ 1][0][ws0] = rBh0; sB[buf ^ 1][0][ws1] = rBh1;
      sB[buf ^ 1][1][ws0] = rBl0; sB[buf ^ 1][1][ws1] = rBl1;
    }
    if ((kt + 64) < K2) {            // issue loads for tile kt+64 (land during compute)
      rAh0 = *(const half8*)(gAh + kt + 64); rAh1 = *(const half8*)(gAh + kt + 72);
      rAl0 = *(const half8*)(gAl + kt + 64); rAl1 = *(const half8*)(gAl + kt + 72);
      rBh0 = *(const half8*)(gBh + kt + 64); rBh1 = *(const half8*)(gBh + kt + 72);
      rBl0 = *(const half8*)(gBl + kt + 64); rBl1 = *(const half8*)(gBl + kt + 72);
    }
#pragma unroll
    for (int s = 0; s < 2; ++s) {
      half8 aH[2], aL[2], bH[2], bL[2];
#pragma unroll
      for (int mf = 0; mf < 2; ++mf) {
        int sa = sa0 + mf * 128 + s * 64;
        aH[mf] = sA[buf][0][sa];
        aL[mf] = sA[buf][1][sa];
      }
#pragma unroll
      for (int nf = 0; nf < 2; ++nf) {
        int sb = sb0 + nf * 128 + s * 64;
        bH[nf] = sB[buf][0][sb];
        bL[nf] = sB[buf][1][sb];
      }
#pragma unroll
      for (int mf = 0; mf < 2; ++mf)
#pragma unroll
        for (int nf = 0; nf < 2; ++nf) {
          accH[mf][nf] =
              __builtin_amdgcn_mfma_f32_32x32x16_f16(aH[mf], bH[nf], accH[mf][nf], 0, 0, 0);
          accL[mf][nf] =
              __builtin_amdgcn_mfma_f32_32x32x16_f16(aH[mf], bL[nf], accL[mf][nf], 0, 0, 0);
          accL[mf][nf] =
              __builtin_amdgcn_mfma_f32_32x32x16_f16(aL[mf], bH[nf], accL[mf][nf], 0, 0, 0);
        }
    }
    if (more) __syncthreads();
  }
  float* Pz = (lz == 2) ? P2 : (P0 + (size_t)(lz == 3 ? 2 : lz) * MN);
  const float sc = 4.8828125e-4f;   // 1/2048
#pragma unroll
  for (int mf = 0; mf < 2; ++mf)
#pragma unroll
    for (int nf = 0; nf < 2; ++nf) {
      int col = n0 + wc * 64 + nf * 32 + fr;
      int rbase = m0 + wr * 64 + mf * 32 + 4 * cgrp;
#pragma unroll
      for (int r = 0; r < 16; ++r) {
        int row = rbase + (r & 3) + ((r >> 2) << 3);
        Pz[(size_t)row * ldc + col] = accH[mf][nf][r] + accL[mf][nf][r] * sc;
      }
    }
}

// ---------------- split-K reduce + bias + relu -> fp16 hi/lo split ----------------
__global__ void k_reduce_split(const float* __restrict__ P0, const float* __restrict__ P2,
                               const float* __restrict__ bias, _Float16* __restrict__ xh,
                               _Float16* __restrict__ xl, int S) {
  const int MN = 2048 * 1024;
  int i8 = blockIdx.x * 256 + threadIdx.x;
  size_t base = (size_t)i8 * 8;
  float v[8];
  {
    float4 a0 = *(const float4*)(P0 + base);
    float4 a1 = *(const float4*)(P0 + base + 4);
    float4 b0 = *(const float4*)(P0 + MN + base);
    float4 b1 = *(const float4*)(P0 + MN + base + 4);
    v[0] = a0.x + b0.x; v[1] = a0.y + b0.y; v[2] = a0.z + b0.z; v[3] = a0.w + b0.w;
    v[4] = a1.x + b1.x; v[5] = a1.y + b1.y; v[6] = a1.z + b1.z; v[7] = a1.w + b1.w;
  }
  if (S == 4) {
    float4 c0 = *(const float4*)(P2 + base);
    float4 c1 = *(const float4*)(P2 + base + 4);
    float4 d0 = *(const float4*)(P0 + 2 * (size_t)MN + base);
    float4 d1 = *(const float4*)(P0 + 2 * (size_t)MN + base + 4);
    v[0] = (v[0] + c0.x) + d0.x; v[1] = (v[1] + c0.y) + d0.y;
    v[2] = (v[2] + c0.z) + d0.z; v[3] = (v[3] + c0.w) + d0.w;
    v[4] = (v[4] + c1.x) + d1.x; v[5] = (v[5] + c1.y) + d1.y;
    v[6] = (v[6] + c1.z) + d1.z; v[7] = (v[7] + c1.w) + d1.w;
  }
  int cb = (int)(base & 1023);
  float4 b0 = *(const float4*)(bias + cb);
  float4 b1v = *(const float4*)(bias + cb + 4);
  v[0] += b0.x; v[1] += b0.y; v[2] += b0.z; v[3] += b0.w;
  v[4] += b1v.x; v[5] += b1v.y; v[6] += b1v.z; v[7] += b1v.w;
  half8 h8, l8;
#pragma unroll
  for (int j = 0; j < 8; ++j) {
    float x = fmaxf(v[j], 0.0f);
    _Float16 h = (_Float16)x;
    h8[j] = h;
    l8[j] = (_Float16)((x - (float)h) * 2048.0f);
  }
  *(half8*)(xh + base) = h8;
  *(half8*)(xl + base) = l8;
}

// ---------------- softmax + decode + keys, fused heads-reduce (4 slices + bias) --------
__global__ __launch_bounds__(256) void k_softmax_decode(const float* __restrict__ PH,
                                                        const float* __restrict__ bh,
                                                        const float* __restrict__ props,
                                                        float* __restrict__ pbox,
                                                        unsigned long long* __restrict__ keys,
                                                        unsigned* __restrict__ cnt) {
  const int MNh = 2048 * 512;
  int wave = threadIdx.x >> 6, lane = threadIdx.x & 63;
  int roi = (blockIdx.x << 2) + wave;
  size_t eb = (size_t)roi * 512;
  // headreduce order preserved: ((z0 + z1) + z2) + z3 + bias,  z2 slice @ +3*MNh
#define HREAD(e) ((((PH[(e)] + PH[(e) + MNh]) + PH[(e) + 3 * (size_t)MNh]) + \
                   PH[(e) + 2 * (size_t)MNh]) + bh[(e) - eb])
  float l0 = HREAD(eb + lane);
  float l1 = (lane < 27) ? HREAD(eb + lane + 64) : -3.4e38f;
  float m = fmaxf(l0, l1);
#pragma unroll
  for (int off = 32; off; off >>= 1) m = fmaxf(m, __shfl_xor(m, off));
  float e0 = expf(l0 - m);
  float e1 = (lane < 27) ? expf(l1 - m) : 0.0f;
  float ssum = e0 + e1;
#pragma unroll
  for (int off = 32; off; off >>= 1) ssum += __shfl_xor(ssum, off);
  const float* pr = props + (size_t)roi * 4;
  float w = pr[2] - pr[0], h = pr[3] - pr[1];
  float cx = pr[0] + 0.5f * w, cy = pr[1] + 0.5f * h;
  int img = roi >> 9, rl = roi & 511;
#pragma unroll
  for (int half = 0; half < 2; ++half) {
    int c = lane + half * 64;
    float e = half ? e1 : e0;
    if (c >= 1 && c <= 90) {
      float score = e / ssum;
      size_t rg = eb + 91 + (c << 2);
      float dx = HREAD(rg + 0) / 10.0f, dy = HREAD(rg + 1) / 10.0f;
      float dw = fminf(HREAD(rg + 2) / 5.0f, BBOX_CLIP_F);
      float dh = fminf(HREAD(rg + 3) / 5.0f, BBOX_CLIP_F);
      float pcx = dx * w + cx, pcy = dy * h + cy;
      float pw = expf(dw) * w, ph = expf(dh) * h;
      float bx1 = pcx - 0.5f * pw, by1 = pcy - 0.5f * ph;
      float bx2 = pcx + 0.5f * pw, by2 = pcy + 0.5f * ph;
      bx1 = fminf(fmaxf(bx1, 0.0f), 800.0f);
      by1 = fminf(fmaxf(by1, 0.0f), 800.0f);
      bx2 = fminf(fmaxf(bx2, 0.0f), 800.0f);
      by2 = fminf(fmaxf(by2, 0.0f), 800.0f);
      float* pb = pbox + ((size_t)roi * 90 + (c - 1)) * 4;
      pb[0] = bx1; pb[1] = by1; pb[2] = bx2; pb[3] = by2;
      if (score > 0.05f && (bx2 - bx1) >= 0.01f && (by2 - by1) >= 0.01f) {
        unsigned pos = atomicAdd(cnt + img, 1u);
        unsigned idx = (unsigned)rl * 90u + (unsigned)(c - 1);
        unsigned su = __float_as_uint(score);
        su ^= (su >> 31) ? 0xFFFFFFFFu : 0x80000000u;
        keys[((size_t)img << 14) + pos] =
            ((unsigned long long)su << 32) | (unsigned long long)(0xFFFFFFFFu - idx);
      }
    }
  }
#undef HREAD
}

// ---------------- per-image bitonic sort of candidate keys (ascending) ----------------
__global__ void k_sort(unsigned long long* __restrict__ keys, const unsigned* __restrict__ cnt) {
  extern __shared__ unsigned long long s[];
  int img = blockIdx.x, tid = threadIdx.x;
  unsigned long long* kb = keys + ((size_t)img << 14);
  unsigned n = cnt[img];
  unsigned np = 2048; while (np < n && np < 16384) np <<= 1;
  if (np <= 8192) {
    for (unsigned i = tid; i < np; i += 1024) s[i] = kb[i];
    __syncthreads();
    for (unsigned k = 2; k <= np; k <<= 1) {
      for (unsigned j = k >> 1; j; j >>= 1) {
        for (unsigned x = tid; x < (np >> 1); x += 1024) {
          unsigned i = ((x & ~(j - 1)) << 1) | (x & (j - 1));
          unsigned l = i | j;
          bool up = ((i & k) == 0);
          unsigned long long a = s[i], b = s[l];
          if ((a > b) == up) { s[i] = b; s[l] = a; }
        }
        __syncthreads();
      }
    }
    for (unsigned i = tid; i < np; i += 1024) kb[i] = s[i];
  } else {
    for (int ch = 0; ch < 2; ++ch) {
      unsigned base = (unsigned)ch << 13;
      for (unsigned i = tid; i < 8192; i += 1024) s[i] = kb[base + i];
      __syncthreads();
      for (unsigned k = 2; k <= 8192; k <<= 1) {
        for (unsigned j = k >> 1; j; j >>= 1) {
          for (unsigned x = tid; x < 4096; x += 1024) {
            unsigned i = ((x & ~(j - 1)) << 1) | (x & (j - 1));
            unsigned l = i | j;
            bool up = (((base + i) & k) == 0);
            unsigned long long a = s[i], b = s[l];
            if ((a > b) == up) { s[i] = b; s[l] = a; }
          }
          __syncthreads();
        }
      }
      for (unsigned i = tid; i < 8192; i += 1024) kb[base + i] = s[i];
      __syncthreads();
    }
    for (unsigned x = tid; x < 8192; x += 1024) {
      unsigned long long a = kb[x], b = kb[x + 8192];
      if (a > b) { kb[x] = b; kb[x + 8192] = a; }
    }
    __syncthreads();
    for (int ch = 0; ch < 2; ++ch) {
      unsigned base = (unsigned)ch << 13;
      for (unsigned i = tid; i < 8192; i += 1024) s[i] = kb[base + i];
      __syncthreads();
      for (unsigned j = 4096; j; j >>= 1) {
        for (unsigned x = tid; x < 4096; x += 1024) {
          unsigned i = ((x & ~(j - 1)) << 1) | (x & (j - 1));
          unsigned l = i | j;
          unsigned long long a = s[i], b = s[l];
          if (a > b) { s[i] = b; s[l] = a; }
        }
        __syncthreads();
      }
      for (unsigned i = tid; i < 8192; i += 1024) kb[base + i] = s[i];
      __syncthreads();
    }
  }
}

// ---------------- gather top-2048 per image into NMS arrays ----------------
__global__ void k_gather(const unsigned long long* __restrict__ keys,
                         const unsigned* __restrict__ cnt, const float* __restrict__ pbox,
                         float4* __restrict__ nmsbox, float4* __restrict__ outbox,
                         float* __restrict__ score, float* __restrict__ label) {
  int g = blockIdx.x * 256 + threadIdx.x;
  int img = g >> 11, slot = g & 2047;
  unsigned n = cnt[img];
  unsigned neff = n > 2048u ? 2048u : n;
  unsigned np = 2048; while (np < n && np < 16384) np <<= 1;
  float4 bo = make_float4(0, 0, 0, 0), bx = make_float4(0, 0, 0, 0);
  float sc = -1.0f, lb = 0.0f;
  if ((unsigned)slot < neff) {
    unsigned long long key = keys[((size_t)img << 14) + (np - 1 - slot)];
    unsigned su = (unsigned)(key >> 32);
    su = (su & 0x80000000u) ? (su ^ 0x80000000u) : ~su;
    sc = __uint_as_float(su);
    unsigned idx = 0xFFFFFFFFu - (unsigned)(key & 0xFFFFFFFFull);
    unsigned rl = idx / 90u, c = idx - rl * 90u;
    const float* pb = pbox + ((size_t)((img << 9) + rl) * 90 + c) * 4;
    bx = *(const float4*)pb;
    float off = (float)(c + 1) * 801.0f;
    bo = make_float4(bx.x + off, bx.y + off, bx.z + off, bx.w + off);
    lb = (float)(c + 1);
  }
  nmsbox[g] = bo; outbox[g] = bx; score[g] = sc; label[g] = lb;
}

// ---------------- IoU bitmask ----------------
__global__ __launch_bounds__(256) void k_mask(const float* __restrict__ nmsbox,
                                              unsigned* __restrict__ mask) {
  __shared__ float bx[2048 * 4];
  int img = blockIdx.x >> 9;
  int i0 = (blockIdx.x & 511) << 2;
  const float4* src = (const float4*)(nmsbox + (size_t)img * 2048 * 4);
  for (int q = threadIdx.x; q < 2048; q += 256) ((float4*)bx)[q] = src[q];
  __syncthreads();
  int w = threadIdx.x & 63, ir = threadIdx.x >> 6;
  int i = i0 + ir;
  float ax1 = bx[i * 4], ay1 = bx[i * 4 + 1], ax2 = bx[i * 4 + 2], ay2 = bx[i * 4 + 3];
  float areaA = (ax2 - ax1) * (ay2 - ay1);
  unsigned bits = 0;
  for (int jj = 0; jj < 32; ++jj) {
    int j2 = (jj + w) & 31;
    int j = (w << 5) + j2;
    float b1 = bx[j * 4], b2 = bx[j * 4 + 1], b3 = bx[j * 4 + 2], b4 = bx[j * 4 + 3];
    float areaB = (b3 - b1) * (b4 - b2);
    float lx = fmaxf(ax1, b1), lyv = fmaxf(ay1, b2);
    float rx = fminf(ax2, b3), ry = fminf(ay2, b4);
    float iw = fmaxf(rx - lx, 0.0f), ih = fmaxf(ry - lyv, 0.0f);
    float inter = iw * ih;
    float iou = inter / (areaA + areaB - inter);
    if (iou > 0.5f) bits |= (1u << j2);
  }
  mask[((size_t)img * 2048 + i) * 64 + w] = bits;
}

// ---------------- sequential greedy NMS scan + output emit ----------------
__global__ void k_scan(const unsigned* __restrict__ mask, const unsigned* __restrict__ cnt,
                       const float* __restrict__ outbox, const float* __restrict__ score,
                       const float* __restrict__ label, float* __restrict__ dout) {
  int img = blockIdx.x, lane = threadIdx.x;
  unsigned n = cnt[img];
  unsigned neff = n > 2048u ? 2048u : n;
  unsigned base = (unsigned)lane * 32u;
  unsigned rem;
  if (base + 32u <= neff) rem = 0u;
  else if (base >= neff) rem = 0xFFFFFFFFu;
  else rem = ~((1u << (neff - base)) - 1u);
  const unsigned* mrow = mask + (size_t)img * 2048 * 64;
  unsigned row = (neff > 0) ? mrow[lane] : 0u;
  int outc = 0;
  for (int i = 0; i < (int)neff; ++i) {
    unsigned nextrow = (i + 1 < (int)neff) ? mrow[(size_t)(i + 1) * 64 + lane] : 0u;
    unsigned wrd = __shfl(rem, i >> 5);
    bool kept = ((wrd >> (i & 31)) & 1u) == 0u;
    if (kept) {
      rem |= row;
      if (lane < 4)
        dout[(size_t)(img * 100 + outc) * 4 + lane] = outbox[((size_t)img * 2048 + i) * 4 + lane];
      if (lane == 0) {
        dout[1600 + img * 100 + outc] = score[img * 2048 + i];
        dout[2000 + img * 100 + outc] = label[img * 2048 + i];
      }
      ++outc;
      if (outc >= 100) break;
    }
    row = nextrow;
  }
}

// ---------------- host launch ----------------
extern "C" void kernel_launch(void* const* d_in, const int* in_sizes, int n_in,
                              void* d_out, int out_size, void* d_ws, size_t ws_size,
                              hipStream_t stream) {
  if (ws_size < WS_NEED) return;

  const float* features  = (const float*)d_in[0];
  const float* proposals = (const float*)d_in[1];
  const float* W1 = (const float*)d_in[2];
  const float* b1 = (const float*)d_in[3];
  const float* W2 = (const float*)d_in[4];
  const float* b2 = (const float*)d_in[5];
  const float* Wc = (const float*)d_in[6];
  const float* bc = (const float*)d_in[7];
  const float* Wr = (const float*)d_in[8];
  const float* br = (const float*)d_in[9];
  float* out = (float*)d_out;
  char* ws = (char*)d_ws;

  float* featT = (float*)(ws + 0);
  _Float16* Ahg = (_Float16*)(ws + O_AH);
  _Float16* Alg = (_Float16*)(ws + O_AL);
  _Float16* Wth = (_Float16*)(ws + O_WTH);
  _Float16* Wtl = (_Float16*)(ws + O_WTL);
  float* partZ = (float*)(ws + OZ);              // FC1 slices z0,z1,z3; FC2 slices z0,z1,z3
  float* partF = (float*)(ws + 0);               // FC1 slice z2 (featT dead)
  _Float16* x1h = (_Float16*)(ws + O_X1H);
  _Float16* x1l = (_Float16*)(ws + O_X1L);
  _Float16* W2th = (_Float16*)(ws + O_W2TH);
  _Float16* W2tl = (_Float16*)(ws + O_W2TL);
  _Float16* x2h = (_Float16*)(ws + O_X2H);
  _Float16* x2l = (_Float16*)(ws + O_X2L);
  _Float16* whh = (_Float16*)(ws + O_WHH);
  _Float16* whl = (_Float16*)(ws + O_WHL);
  float* bhv   = (float*)(ws + O_BH);
  float* partH = (float*)(ws + O_PARTH);         // heads P0 (3 slices); FC2 P2 slice
  float* partH2 = (float*)(ws + O_PARTH + 3ull * 4194304ull);
  float* pbox  = (float*)(ws + O_PBOX);
  unsigned long long* keys = (unsigned long long*)(ws + O_KEYS);
  float* nmsbox = (float*)(ws + O_NMSBOX);
  float* outbox = (float*)(ws + O_OUTBOX);
  float* scorea = (float*)(ws + O_SCORE);
  float* labela = (float*)(ws + O_LABEL);
  unsigned* cnt = (unsigned*)(ws + O_CNT);
  unsigned* maska = (unsigned*)(ws + O_MASK);

  k_transpose<<<dim3(79, 8, 4), 256, 0, stream>>>(features, featT, out);
  k_wsplit<<<dim3(196, 16), 256, 0, stream>>>(W1, Wth, Wtl, 12544, 1024);
  k_roialign<<<2048, 256, 0, stream>>>(featT, proposals, Ahg, Alg);
  // FC1: [2048,12544] x [12544,1024], split-K=4 (z0,z1,z3 @OZ; z2 @featT region)
  k_mfma<<<dim3(8, 16, 4), 256, 0, stream>>>(Ahg, Alg, Wth, Wtl, partZ, partF,
                                             12544, 3136, 1024, 2048 * 1024);
  k_reduce_split<<<1024, 256, 0, stream>>>(partZ, partF, b1, x1h, x1l, 4);
  k_prep2<<<768, 256, 0, stream>>>(W2, Wc, Wr, bc, br, W2th, W2tl, whh, whl, bhv,
                                   (unsigned*)keys, cnt);
  // FC2: [2048,1024] x [1024,1024], split-K=4 (z0,z1,z3 @OZ; z2 @partH region)
  k_mfma<<<dim3(8, 16, 4), 256, 0, stream>>>(x1h, x1l, W2th, W2tl, partZ, partH,
                                             1024, 256, 1024, 2048 * 1024);
  k_reduce_split<<<1024, 256, 0, stream>>>(partZ, partH, b2, x2h, x2l, 4);
  // heads: [2048,1024] x [1024,512], split-K=4
  k_mfma<<<dim3(4, 16, 4), 256, 0, stream>>>(x2h, x2l, whh, whl, partH, partH2,
                                             1024, 256, 512, 2048 * 512);
  k_softmax_decode<<<512, 256, 0, stream>>>(partH, bhv, proposals, pbox, keys, cnt);
  k_sort<<<4, 1024, 65536, stream>>>(keys, cnt);
  k_gather<<<32, 256, 0, stream>>>(keys, cnt, pbox, (float4*)nmsbox, (float4*)outbox,
                                   scorea, labela);
  k_mask<<<2048, 256, 0, stream>>>(nmsbox, maska);
  k_scan<<<4, 64, 0, stream>>>(maska, cnt, outbox, scorea, labela, out);
}

// Round 15
// 367.089 us; speedup vs baseline: 1.0189x; 1.0189x over previous
//
#include <hip/hip_runtime.h>
#include <stdint.h>

// ---------------- problem constants ----------------
#define NBI 4
#define RRI 512
#define NROI 2048
#define DIN 12544      // 256*7*7
#define BBOX_CLIP_F 4.135166556742356f

typedef _Float16 half8 __attribute__((ext_vector_type(8)));
typedef float f32x16 __attribute__((ext_vector_type(16)));

// ---------------- workspace layout (bytes) ----------------
#define O_AH      10240000ull
#define O_AL      61620224ull
#define O_WTH     113000448ull
#define O_WTL     138690560ull
#define OZ        164380672ull
#define WS_NEED   189546496ull

#define O_X2H     0ull
#define O_X2L     2097152ull
#define O_X1H     O_AH
#define O_X1L     (O_AH + 4194304ull)
#define O_PBOX    O_AL
#define O_KEYS    (O_AL + 2949120ull)
#define O_NMSBOX  (O_AL + 3473408ull)
#define O_OUTBOX  (O_AL + 3604480ull)
#define O_SCORE   (O_AL + 3735552ull)
#define O_LABEL   (O_AL + 3768320ull)
#define O_CNT     (O_AL + 3801088ull)
#define O_MASK    (O_AL + 3802112ull)
#define O_WHH     O_WTH
#define O_WHL     (O_WTH + 1048576ull)
#define O_BH      (O_WTH + 2097152ull)
#define O_PARTH   (O_WTH + 2101248ull)
#define O_W2TH    OZ
#define O_W2TL    (OZ + 2097152ull)
#define O_PFC2    (OZ + 4194304ull)

// ---------------- features transpose + d_out zero (fused) ----------------
__global__ __launch_bounds__(256) void k_transpose(const float* __restrict__ f,
                                                   float* __restrict__ ft,
                                                   float* __restrict__ out) {
  __shared__ float s[32][33];
  int b = blockIdx.z;
  int hw0 = blockIdx.x << 5;
  int c0 = blockIdx.y << 5;
  if (blockIdx.y == 0 && blockIdx.z == 0 && blockIdx.x < 10) {
    int i = blockIdx.x * 256 + threadIdx.x;
    if (i < 2400) out[i] = 0.0f;
  }
  int tx = threadIdx.x & 31, ty = threadIdx.x >> 5;
#pragma unroll
  for (int j = 0; j < 32; j += 8) {
    int hw = hw0 + tx;
    if (hw < 2500) s[ty + j][tx] = f[((size_t)b * 256 + c0 + ty + j) * 2500 + hw];
  }
  __syncthreads();
#pragma unroll
  for (int j = 0; j < 32; j += 8) {
    int hw = hw0 + ty + j;
    if (hw < 2500) ft[((size_t)b * 2500 + hw) * 256 + c0 + tx] = s[tx][ty + j];
  }
}

// ---------------- W [K][N] f32 -> transposed split Th/Tl [N][K] fp16 ----------------
__global__ __launch_bounds__(256) void k_wsplit(const float* __restrict__ W,
                                                _Float16* __restrict__ Th,
                                                _Float16* __restrict__ Tl, int K, int N) {
  __shared__ float s[64][68];
  int k0 = blockIdx.x << 6, n0 = blockIdx.y << 6;
  int t = threadIdx.x;
  int r = t >> 2, c4 = (t & 3) << 4;
#pragma unroll
  for (int j = 0; j < 16; j += 4) {
    float4 v = *(const float4*)(W + (size_t)(k0 + r) * N + n0 + c4 + j);
    s[r][c4 + j] = v.x; s[r][c4 + j + 1] = v.y; s[r][c4 + j + 2] = v.z; s[r][c4 + j + 3] = v.w;
  }
  __syncthreads();
  int nr = t >> 2, kc = (t & 3) << 4;
  half8 h8[2], l8[2];
#pragma unroll
  for (int j = 0; j < 16; ++j) {
    float v = s[kc + j][nr];
    _Float16 h = (_Float16)v;
    _Float16 lo = (_Float16)((v - (float)h) * 2048.0f);
    h8[j >> 3][j & 7] = h;
    l8[j >> 3][j & 7] = lo;
  }
  size_t base = (size_t)(n0 + nr) * K + k0 + kc;
  *(half8*)(Th + base) = h8[0]; *(half8*)(Th + base + 8) = h8[1];
  *(half8*)(Tl + base) = l8[0]; *(half8*)(Tl + base + 8) = l8[1];
}

// ---------------- fused prep: W2 split (blocks 0..255) + heads split + key/cnt zero ----
__global__ __launch_bounds__(256) void k_prep2(const float* __restrict__ W2,
                                               const float* __restrict__ Wc,
                                               const float* __restrict__ Wr,
                                               const float* __restrict__ bcv,
                                               const float* __restrict__ brv,
                                               _Float16* __restrict__ T2h,
                                               _Float16* __restrict__ T2l,
                                               _Float16* __restrict__ Th,
                                               _Float16* __restrict__ Tl,
                                               float* __restrict__ bh,
                                               unsigned* __restrict__ keys32,
                                               unsigned* __restrict__ cnt) {
  int blk = blockIdx.x;
  int t = threadIdx.x;
  if (blk < 256) {   // W2 [1024][1024] transpose-split, tile (k0,n0)
    __shared__ float s[64][68];
    int k0 = (blk & 15) << 6, n0 = (blk >> 4) << 6;
    int r = t >> 2, c4 = (t & 3) << 4;
#pragma unroll
    for (int j = 0; j < 16; j += 4) {
      float4 v = *(const float4*)(W2 + (size_t)(k0 + r) * 1024 + n0 + c4 + j);
      s[r][c4 + j] = v.x; s[r][c4 + j + 1] = v.y; s[r][c4 + j + 2] = v.z; s[r][c4 + j + 3] = v.w;
    }
    __syncthreads();
    int nr = t >> 2, kc = (t & 3) << 4;
    half8 h8[2], l8[2];
#pragma unroll
    for (int j = 0; j < 16; ++j) {
      float v = s[kc + j][nr];
      _Float16 h = (_Float16)v;
      _Float16 lo = (_Float16)((v - (float)h) * 2048.0f);
      h8[j >> 3][j & 7] = h;
      l8[j >> 3][j & 7] = lo;
    }
    size_t base = (size_t)(n0 + nr) * 1024 + k0 + kc;
    *(half8*)(T2h + base) = h8[0]; *(half8*)(T2h + base + 8) = h8[1];
    *(half8*)(T2l + base) = l8[0]; *(half8*)(T2l + base + 8) = l8[1];
  } else {           // heads weights row n + zero keys/cnt
    int n = blk - 256;          // 0..511
    keys32[(n << 8) + t] = 0u;
    if (n == 0 && t < 64) cnt[t] = 0u;
    for (int k = t; k < 1024; k += 256) {
      float v = (n < 91) ? Wc[(size_t)k * 91 + n]
                         : ((n < 455) ? Wr[(size_t)k * 364 + (n - 91)] : 0.0f);
      _Float16 h = (_Float16)v;
      Th[(size_t)n * 1024 + k] = h;
      Tl[(size_t)n * 1024 + k] = (_Float16)((v - (float)h) * 2048.0f);
    }
    if (t == 0) bh[n] = (n < 91) ? bcv[n] : ((n < 455) ? brv[n - 91] : 0.0f);
  }
}

// ---------------- RoI align -> Ah/Al fp16 split [2048][12544] ----------------
__global__ __launch_bounds__(256) void k_roialign(const float* __restrict__ ft,
                                                  const float* __restrict__ props,
                                                  _Float16* __restrict__ Ahg,
                                                  _Float16* __restrict__ Alg) {
  __shared__ float pool[DIN];
  __shared__ float lyA[7], lxA[7];
  __shared__ int y0A[7], y1A[7], x0A[7], x1A[7];
  int roi = blockIdx.x;
  int b = roi >> 9;
  const float* p = props + (size_t)roi * 4;
  float x1s = p[0] * 0.0625f, y1s = p[1] * 0.0625f;
  float x2s = p[2] * 0.0625f, y2s = p[3] * 0.0625f;
  float bh = (y2s - y1s) / 7.0f;
  float bw = (x2s - x1s) / 7.0f;
  int t = threadIdx.x;
  if (t < 7) {
    float y = y1s + ((float)t + 0.5f) * bh;
    y = fminf(fmaxf(y, 0.0f), 49.0f);
    float y0 = floorf(y);
    int y0i = (int)y0;
    y0A[t] = y0i; y1A[t] = min(y0i + 1, 49); lyA[t] = y - y0;
  } else if (t < 14) {
    int px = t - 7;
    float x = x1s + ((float)px + 0.5f) * bw;
    x = fminf(fmaxf(x, 0.0f), 49.0f);
    float x0 = floorf(x);
    int x0i = (int)x0;
    x0A[px] = x0i; x1A[px] = min(x0i + 1, 49); lxA[px] = x - x0;
  }
  __syncthreads();
  const float* fb = ft + (size_t)b * 2500 * 256;
  int c = t;
  for (int p49 = 0; p49 < 49; ++p49) {
    int py = p49 / 7, px = p49 - py * 7;
    int y0 = y0A[py], y1 = y1A[py], x0 = x0A[px], x1 = x1A[px];
    float ly = lyA[py], lx = lxA[px], hy = 1.0f - ly, hx = 1.0f - lx;
    float f00 = fb[(y0 * 50 + x0) * 256 + c];
    float f01 = fb[(y0 * 50 + x1) * 256 + c];
    float f10 = fb[(y1 * 50 + x0) * 256 + c];
    float f11 = fb[(y1 * 50 + x1) * 256 + c];
    pool[c * 49 + p49] = (hy * hx) * f00 + (hy * lx) * f01 + (ly * hx) * f10 + (ly * lx) * f11;
  }
  __syncthreads();
  _Float16* dh = Ahg + (size_t)roi * DIN;
  _Float16* dl = Alg + (size_t)roi * DIN;
  for (int i8 = t; i8 < 1568; i8 += 256) {   // 1568*8 = 12544, vectorized stores
    half8 h8v, l8v;
#pragma unroll
    for (int j = 0; j < 8; ++j) {
      float v = pool[i8 * 8 + j];
      _Float16 h = (_Float16)v;
      h8v[j] = h;
      l8v[j] = (_Float16)((v - (float)h) * 2048.0f);
    }
    *(half8*)(dh + (size_t)i8 * 8) = h8v;
    *(half8*)(dl + (size_t)i8 * 8) = l8v;
  }
}

// ---------------- MFMA GEMM: 32x32x16 f16, hi/lo 3-term, BM=BN=128, BK=32 -------------
// R11-proven core: 256 threads = 4 waves (2x2); wave tile 64x64.  Both operands staged
// via registers into FRAGMENT-MAJOR LDS (slot ((r>>5)*4+c)*32+(r&31)): staging writes
// and fragment reads are contiguous per 32-lane group => conflict-free.  Double-buffered,
// ONE barrier per K-step; global loads issued 2 tiles ahead.  T1 chunked XCD swizzle.
__global__ __launch_bounds__(256, 2) void k_mfma(const _Float16* __restrict__ Ah,
                                                 const _Float16* __restrict__ Al,
                                                 const _Float16* __restrict__ Bh,
                                                 const _Float16* __restrict__ Bl,
                                                 float* __restrict__ P0,
                                                 float* __restrict__ P2,
                                                 int K, int K2, int ldc, int MN) {
  __shared__ __align__(16) half8 sA[2][2][512];   // [buf][hi/lo][slot]
  __shared__ __align__(16) half8 sB[2][2][512];
  int gx = gridDim.x, gy = gridDim.y;
  int nwg = gx * gy * gridDim.z;
  int lin = blockIdx.x + gx * (blockIdx.y + gy * blockIdx.z);
  int cpx = nwg >> 3;                     // all grids are multiples of 8
  int nl = (lin & 7) * cpx + (lin >> 3);  // bijective chunked T1 remap
  int sx = __ffs(gx) - 1, sy = __ffs(gy) - 1;
  int lx = nl & (gx - 1);
  int rest = nl >> sx;
  int ly = rest & (gy - 1);
  int lz = rest >> sy;
  int m0 = ly << 7, n0 = lx << 7;
  int kb = lz * K2;
  int t = threadIdx.x;
  int w = t >> 6, l = t & 63;
  int wr = w >> 1, wc = w & 1;
  int fr = l & 31, cgrp = l >> 5;
  // staging: thread stages row sr, chunks {2*sh, 2*sh+1} (32B) per array
  int sr = t >> 1, sh = t & 1;
  const _Float16* gAh = Ah + (size_t)(m0 + sr) * K + kb + sh * 16;
  const _Float16* gAl = Al + (size_t)(m0 + sr) * K + kb + sh * 16;
  const _Float16* gBh = Bh + (size_t)(n0 + sr) * K + kb + sh * 16;
  const _Float16* gBl = Bl + (size_t)(n0 + sr) * K + kb + sh * 16;
  int ws0 = ((sr >> 5) * 4 + 2 * sh) * 32 + (sr & 31);  // fragment-major dest slots
  int ws1 = ws0 + 32;
  // fragment read slot bases: slot(mf,s) = base + mf*128 + s*64
  int sa0 = wr * 256 + cgrp * 32 + fr;
  int sb0 = wc * 256 + cgrp * 32 + fr;
  f32x16 accH[2][2], accL[2][2];
#pragma unroll
  for (int i = 0; i < 2; ++i)
#pragma unroll
    for (int j = 0; j < 2; ++j)
#pragma unroll
      for (int r = 0; r < 16; ++r) { accH[i][j][r] = 0.0f; accL[i][j][r] = 0.0f; }
  // prologue: tile0 -> buf0; prefetch tile1 into regs
  half8 rAh0 = *(const half8*)gAh, rAh1 = *(const half8*)(gAh + 8);
  half8 rAl0 = *(const half8*)gAl, rAl1 = *(const half8*)(gAl + 8);
  half8 rBh0 = *(const half8*)gBh, rBh1 = *(const half8*)(gBh + 8);
  half8 rBl0 = *(const half8*)gBl, rBl1 = *(const half8*)(gBl + 8);
  sA[0][0][ws0] = rAh0; sA[0][0][ws1] = rAh1;
  sA[0][1][ws0] = rAl0; sA[0][1][ws1] = rAl1;
  sB[0][0][ws0] = rBh0; sB[0][0][ws1] = rBh1;
  sB[0][1][ws0] = rBl0; sB[0][1][ws1] = rBl1;
  if (32 < K2) {
    rAh0 = *(const half8*)(gAh + 32); rAh1 = *(const half8*)(gAh + 40);
    rAl0 = *(const half8*)(gAl + 32); rAl1 = *(const half8*)(gAl + 40);
    rBh0 = *(const half8*)(gBh + 32); rBh1 = *(const half8*)(gBh + 40);
    rBl0 = *(const half8*)(gBl + 32); rBl1 = *(const half8*)(gBl + 40);
  }
  __syncthreads();
  for (int kt = 0; kt < K2; kt += 32) {
    int buf = (kt >> 5) & 1;
    bool more = (kt + 32) < K2;
    if (more) {                      // write tile kt+32 (in regs) into buf^1
      sA[buf ^ 1][0][ws0] = rAh0; sA[buf ^ 1][0][ws1] = rAh1;
      sA[buf ^ 1][1][ws0] = rAl0; sA[buf ^ 1][1][ws1] = rAl1;
      sB[buf ^ 1][0][ws0] = rBh0; sB[buf ^ 1][0][ws1] = rBh1;
      sB[buf ^ 1][1][ws0] = rBl0; sB[buf ^ 1][1][ws1] = rBl1;
    }
    if ((kt + 64) < K2) {            // issue loads for tile kt+64 (land during compute)
      rAh0 = *(const half8*)(gAh + kt + 64); rAh1 = *(const half8*)(gAh + kt + 72);
      rAl0 = *(const half8*)(gAl + kt + 64); rAl1 = *(const half8*)(gAl + kt + 72);
      rBh0 = *(const half8*)(gBh + kt + 64); rBh1 = *(const half8*)(gBh + kt + 72);
      rBl0 = *(const half8*)(gBl + kt + 64); rBl1 = *(const half8*)(gBl + kt + 72);
    }
#pragma unroll
    for (int s = 0; s < 2; ++s) {
      half8 aH[2], aL[2], bH[2], bL[2];
#pragma unroll
      for (int mf = 0; mf < 2; ++mf) {
        int sa = sa0 + mf * 128 + s * 64;
        aH[mf] = sA[buf][0][sa];
        aL[mf] = sA[buf][1][sa];
      }
#pragma unroll
      for (int nf = 0; nf < 2; ++nf) {
        int sb = sb0 + nf * 128 + s * 64;
        bH[nf] = sB[buf][0][sb];
        bL[nf] = sB[buf][1][sb];
      }
#pragma unroll
      for (int mf = 0; mf < 2; ++mf)
#pragma unroll
        for (int nf = 0; nf < 2; ++nf) {
          accH[mf][nf] =
              __builtin_amdgcn_mfma_f32_32x32x16_f16(aH[mf], bH[nf], accH[mf][nf], 0, 0, 0);
          accL[mf][nf] =
              __builtin_amdgcn_mfma_f32_32x32x16_f16(aH[mf], bL[nf], accL[mf][nf], 0, 0, 0);
          accL[mf][nf] =
              __builtin_amdgcn_mfma_f32_32x32x16_f16(aL[mf], bH[nf], accL[mf][nf], 0, 0, 0);
        }
    }
    if (more) __syncthreads();
  }
  float* Pz = (lz == 2) ? P2 : (P0 + (size_t)(lz == 3 ? 2 : lz) * MN);
  const float sc = 4.8828125e-4f;   // 1/2048
#pragma unroll
  for (int mf = 0; mf < 2; ++mf)
#pragma unroll
    for (int nf = 0; nf < 2; ++nf) {
      int col = n0 + wc * 64 + nf * 32 + fr;
      int rbase = m0 + wr * 64 + mf * 32 + 4 * cgrp;
#pragma unroll
      for (int r = 0; r < 16; ++r) {
        int row = rbase + (r & 3) + ((r >> 2) << 3);
        Pz[(size_t)row * ldc + col] = accH[mf][nf][r] + accL[mf][nf][r] * sc;
      }
    }
}

// ---------------- split-K reduce + bias + relu -> fp16 hi/lo split ----------------
__global__ void k_reduce_split(const float* __restrict__ P0, const float* __restrict__ P2,
                               const float* __restrict__ bias, _Float16* __restrict__ xh,
                               _Float16* __restrict__ xl, int S) {
  const int MN = 2048 * 1024;
  int i8 = blockIdx.x * 256 + threadIdx.x;
  size_t base = (size_t)i8 * 8;
  float v[8];
  {
    float4 a0 = *(const float4*)(P0 + base);
    float4 a1 = *(const float4*)(P0 + base + 4);
    float4 b0 = *(const float4*)(P0 + MN + base);
    float4 b1 = *(const float4*)(P0 + MN + base + 4);
    v[0] = a0.x + b0.x; v[1] = a0.y + b0.y; v[2] = a0.z + b0.z; v[3] = a0.w + b0.w;
    v[4] = a1.x + b1.x; v[5] = a1.y + b1.y; v[6] = a1.z + b1.z; v[7] = a1.w + b1.w;
  }
  if (S == 4) {
    float4 c0 = *(const float4*)(P2 + base);
    float4 c1 = *(const float4*)(P2 + base + 4);
    float4 d0 = *(const float4*)(P0 + 2 * (size_t)MN + base);
    float4 d1 = *(const float4*)(P0 + 2 * (size_t)MN + base + 4);
    v[0] = (v[0] + c0.x) + d0.x; v[1] = (v[1] + c0.y) + d0.y;
    v[2] = (v[2] + c0.z) + d0.z; v[3] = (v[3] + c0.w) + d0.w;
    v[4] = (v[4] + c1.x) + d1.x; v[5] = (v[5] + c1.y) + d1.y;
    v[6] = (v[6] + c1.z) + d1.z; v[7] = (v[7] + c1.w) + d1.w;
  }
  int cb = (int)(base & 1023);
  float4 b0 = *(const float4*)(bias + cb);
  float4 b1v = *(const float4*)(bias + cb + 4);
  v[0] += b0.x; v[1] += b0.y; v[2] += b0.z; v[3] += b0.w;
  v[4] += b1v.x; v[5] += b1v.y; v[6] += b1v.z; v[7] += b1v.w;
  half8 h8, l8;
#pragma unroll
  for (int j = 0; j < 8; ++j) {
    float x = fmaxf(v[j], 0.0f);
    _Float16 h = (_Float16)x;
    h8[j] = h;
    l8[j] = (_Float16)((x - (float)h) * 2048.0f);
  }
  *(half8*)(xh + base) = h8;
  *(half8*)(xl + base) = l8;
}

// ---------------- softmax + decode + keys, fused heads-reduce (4 slices + bias) --------
__global__ __launch_bounds__(256) void k_softmax_decode(const float* __restrict__ PH,
                                                        const float* __restrict__ bh,
                                                        const float* __restrict__ props,
                                                        float* __restrict__ pbox,
                                                        unsigned long long* __restrict__ keys,
                                                        unsigned* __restrict__ cnt) {
  const int MNh = 2048 * 512;
  int wave = threadIdx.x >> 6, lane = threadIdx.x & 63;
  int roi = (blockIdx.x << 2) + wave;
  size_t eb = (size_t)roi * 512;
  // headreduce order preserved: ((z0 + z1) + z2) + z3 + bias,  z2 slice @ +3*MNh
#define HREAD(e) ((((PH[(e)] + PH[(e) + MNh]) + PH[(e) + 3 * (size_t)MNh]) + \
                   PH[(e) + 2 * (size_t)MNh]) + bh[(e) - eb])
  float l0 = HREAD(eb + lane);
  float l1 = (lane < 27) ? HREAD(eb + lane + 64) : -3.4e38f;
  float m = fmaxf(l0, l1);
#pragma unroll
  for (int off = 32; off; off >>= 1) m = fmaxf(m, __shfl_xor(m, off));
  float e0 = expf(l0 - m);
  float e1 = (lane < 27) ? expf(l1 - m) : 0.0f;
  float ssum = e0 + e1;
#pragma unroll
  for (int off = 32; off; off >>= 1) ssum += __shfl_xor(ssum, off);
  const float* pr = props + (size_t)roi * 4;
  float w = pr[2] - pr[0], h = pr[3] - pr[1];
  float cx = pr[0] + 0.5f * w, cy = pr[1] + 0.5f * h;
  int img = roi >> 9, rl = roi & 511;
#pragma unroll
  for (int half = 0; half < 2; ++half) {
    int c = lane + half * 64;
    float e = half ? e1 : e0;
    if (c >= 1 && c <= 90) {
      float score = e / ssum;
      size_t rg = eb + 91 + (c << 2);
      float dx = HREAD(rg + 0) / 10.0f, dy = HREAD(rg + 1) / 10.0f;
      float dw = fminf(HREAD(rg + 2) / 5.0f, BBOX_CLIP_F);
      float dh = fminf(HREAD(rg + 3) / 5.0f, BBOX_CLIP_F);
      float pcx = dx * w + cx, pcy = dy * h + cy;
      float pw = expf(dw) * w, ph = expf(dh) * h;
      float bx1 = pcx - 0.5f * pw, by1 = pcy - 0.5f * ph;
      float bx2 = pcx + 0.5f * pw, by2 = pcy + 0.5f * ph;
      bx1 = fminf(fmaxf(bx1, 0.0f), 800.0f);
      by1 = fminf(fmaxf(by1, 0.0f), 800.0f);
      bx2 = fminf(fmaxf(bx2, 0.0f), 800.0f);
      by2 = fminf(fmaxf(by2, 0.0f), 800.0f);
      float* pb = pbox + ((size_t)roi * 90 + (c - 1)) * 4;
      pb[0] = bx1; pb[1] = by1; pb[2] = bx2; pb[3] = by2;
      if (score > 0.05f && (bx2 - bx1) >= 0.01f && (by2 - by1) >= 0.01f) {
        unsigned pos = atomicAdd(cnt + img, 1u);
        unsigned idx = (unsigned)rl * 90u + (unsigned)(c - 1);
        unsigned su = __float_as_uint(score);
        su ^= (su >> 31) ? 0xFFFFFFFFu : 0x80000000u;
        keys[((size_t)img << 14) + pos] =
            ((unsigned long long)su << 32) | (unsigned long long)(0xFFFFFFFFu - idx);
      }
    }
  }
#undef HREAD
}

// ---------------- per-image bitonic sort of candidate keys (ascending) ----------------
__global__ void k_sort(unsigned long long* __restrict__ keys, const unsigned* __restrict__ cnt) {
  extern __shared__ unsigned long long s[];
  int img = blockIdx.x, tid = threadIdx.x;
  unsigned long long* kb = keys + ((size_t)img << 14);
  unsigned n = cnt[img];
  unsigned np = 2048; while (np < n && np < 16384) np <<= 1;
  if (np <= 8192) {
    for (unsigned i = tid; i < np; i += 1024) s[i] = kb[i];
    __syncthreads();
    for (unsigned k = 2; k <= np; k <<= 1) {
      for (unsigned j = k >> 1; j; j >>= 1) {
        for (unsigned x = tid; x < (np >> 1); x += 1024) {
          unsigned i = ((x & ~(j - 1)) << 1) | (x & (j - 1));
          unsigned l = i | j;
          bool up = ((i & k) == 0);
          unsigned long long a = s[i], b = s[l];
          if ((a > b) == up) { s[i] = b; s[l] = a; }
        }
        __syncthreads();
      }
    }
    for (unsigned i = tid; i < np; i += 1024) kb[i] = s[i];
  } else {
    for (int ch = 0; ch < 2; ++ch) {
      unsigned base = (unsigned)ch << 13;
      for (unsigned i = tid; i < 8192; i += 1024) s[i] = kb[base + i];
      __syncthreads();
      for (unsigned k = 2; k <= 8192; k <<= 1) {
        for (unsigned j = k >> 1; j; j >>= 1) {
          for (unsigned x = tid; x < 4096; x += 1024) {
            unsigned i = ((x & ~(j - 1)) << 1) | (x & (j - 1));
            unsigned l = i | j;
            bool up = (((base + i) & k) == 0);
            unsigned long long a = s[i], b = s[l];
            if ((a > b) == up) { s[i] = b; s[l] = a; }
          }
          __syncthreads();
        }
      }
      for (unsigned i = tid; i < 8192; i += 1024) kb[base + i] = s[i];
      __syncthreads();
    }
    for (unsigned x = tid; x < 8192; x += 1024) {
      unsigned long long a = kb[x], b = kb[x + 8192];
      if (a > b) { kb[x] = b; kb[x + 8192] = a; }
    }
    __syncthreads();
    for (int ch = 0; ch < 2; ++ch) {
      unsigned base = (unsigned)ch << 13;
      for (unsigned i = tid; i < 8192; i += 1024) s[i] = kb[base + i];
      __syncthreads();
      for (unsigned j = 4096; j; j >>= 1) {
        for (unsigned x = tid; x < 4096; x += 1024) {
          unsigned i = ((x & ~(j - 1)) << 1) | (x & (j - 1));
          unsigned l = i | j;
          unsigned long long a = s[i], b = s[l];
          if (a > b) { s[i] = b; s[l] = a; }
        }
        __syncthreads();
      }
      for (unsigned i = tid; i < 8192; i += 1024) kb[base + i] = s[i];
      __syncthreads();
    }
  }
}

// ---------------- gather top-2048 per image into NMS arrays ----------------
__global__ void k_gather(const unsigned long long* __restrict__ keys,
                         const unsigned* __restrict__ cnt, const float* __restrict__ pbox,
                         float4* __restrict__ nmsbox, float4* __restrict__ outbox,
                         float* __restrict__ score, float* __restrict__ label) {
  int g = blockIdx.x * 256 + threadIdx.x;
  int img = g >> 11, slot = g & 2047;
  unsigned n = cnt[img];
  unsigned neff = n > 2048u ? 2048u : n;
  unsigned np = 2048; while (np < n && np < 16384) np <<= 1;
  float4 bo = make_float4(0, 0, 0, 0), bx = make_float4(0, 0, 0, 0);
  float sc = -1.0f, lb = 0.0f;
  if ((unsigned)slot < neff) {
    unsigned long long key = keys[((size_t)img << 14) + (np - 1 - slot)];
    unsigned su = (unsigned)(key >> 32);
    su = (su & 0x80000000u) ? (su ^ 0x80000000u) : ~su;
    sc = __uint_as_float(su);
    unsigned idx = 0xFFFFFFFFu - (unsigned)(key & 0xFFFFFFFFull);
    unsigned rl = idx / 90u, c = idx - rl * 90u;
    const float* pb = pbox + ((size_t)((img << 9) + rl) * 90 + c) * 4;
    bx = *(const float4*)pb;
    float off = (float)(c + 1) * 801.0f;
    bo = make_float4(bx.x + off, bx.y + off, bx.z + off, bx.w + off);
    lb = (float)(c + 1);
  }
  nmsbox[g] = bo; outbox[g] = bx; score[g] = sc; label[g] = lb;
}

// ---------------- IoU bitmask ----------------
__global__ __launch_bounds__(256) void k_mask(const float* __restrict__ nmsbox,
                                              unsigned* __restrict__ mask) {
  __shared__ float bx[2048 * 4];
  int img = blockIdx.x >> 9;
  int i0 = (blockIdx.x & 511) << 2;
  const float4* src = (const float4*)(nmsbox + (size_t)img * 2048 * 4);
  for (int q = threadIdx.x; q < 2048; q += 256) ((float4*)bx)[q] = src[q];
  __syncthreads();
  int w = threadIdx.x & 63, ir = threadIdx.x >> 6;
  int i = i0 + ir;
  float ax1 = bx[i * 4], ay1 = bx[i * 4 + 1], ax2 = bx[i * 4 + 2], ay2 = bx[i * 4 + 3];
  float areaA = (ax2 - ax1) * (ay2 - ay1);
  unsigned bits = 0;
  for (int jj = 0; jj < 32; ++jj) {
    int j2 = (jj + w) & 31;
    int j = (w << 5) + j2;
    float b1 = bx[j * 4], b2 = bx[j * 4 + 1], b3 = bx[j * 4 + 2], b4 = bx[j * 4 + 3];
    float areaB = (b3 - b1) * (b4 - b2);
    float lx = fmaxf(ax1, b1), lyv = fmaxf(ay1, b2);
    float rx = fminf(ax2, b3), ry = fminf(ay2, b4);
    float iw = fmaxf(rx - lx, 0.0f), ih = fmaxf(ry - lyv, 0.0f);
    float inter = iw * ih;
    float iou = inter / (areaA + areaB - inter);
    if (iou > 0.5f) bits |= (1u << j2);
  }
  mask[((size_t)img * 2048 + i) * 64 + w] = bits;
}

// ---------------- sequential greedy NMS scan + output emit ----------------
__global__ void k_scan(const unsigned* __restrict__ mask, const unsigned* __restrict__ cnt,
                       const float* __restrict__ outbox, const float* __restrict__ score,
                       const float* __restrict__ label, float* __restrict__ dout) {
  int img = blockIdx.x, lane = threadIdx.x;
  unsigned n = cnt[img];
  unsigned neff = n > 2048u ? 2048u : n;
  unsigned base = (unsigned)lane * 32u;
  unsigned rem;
  if (base + 32u <= neff) rem = 0u;
  else if (base >= neff) rem = 0xFFFFFFFFu;
  else rem = ~((1u << (neff - base)) - 1u);
  const unsigned* mrow = mask + (size_t)img * 2048 * 64;
  unsigned row = (neff > 0) ? mrow[lane] : 0u;
  int outc = 0;
  for (int i = 0; i < (int)neff; ++i) {
    unsigned nextrow = (i + 1 < (int)neff) ? mrow[(size_t)(i + 1) * 64 + lane] : 0u;
    unsigned wrd = __shfl(rem, i >> 5);
    bool kept = ((wrd >> (i & 31)) & 1u) == 0u;
    if (kept) {
      rem |= row;
      if (lane < 4)
        dout[(size_t)(img * 100 + outc) * 4 + lane] = outbox[((size_t)img * 2048 + i) * 4 + lane];
      if (lane == 0) {
        dout[1600 + img * 100 + outc] = score[img * 2048 + i];
        dout[2000 + img * 100 + outc] = label[img * 2048 + i];
      }
      ++outc;
      if (outc >= 100) break;
    }
    row = nextrow;
  }
}

// ---------------- host launch ----------------
extern "C" void kernel_launch(void* const* d_in, const int* in_sizes, int n_in,
                              void* d_out, int out_size, void* d_ws, size_t ws_size,
                              hipStream_t stream) {
  if (ws_size < WS_NEED) return;

  const float* features  = (const float*)d_in[0];
  const float* proposals = (const float*)d_in[1];
  const float* W1 = (const float*)d_in[2];
  const float* b1 = (const float*)d_in[3];
  const float* W2 = (const float*)d_in[4];
  const float* b2 = (const float*)d_in[5];
  const float* Wc = (const float*)d_in[6];
  const float* bc = (const float*)d_in[7];
  const float* Wr = (const float*)d_in[8];
  const float* br = (const float*)d_in[9];
  float* out = (float*)d_out;
  char* ws = (char*)d_ws;

  float* featT = (float*)(ws + 0);
  _Float16* Ahg = (_Float16*)(ws + O_AH);
  _Float16* Alg = (_Float16*)(ws + O_AL);
  _Float16* Wth = (_Float16*)(ws + O_WTH);
  _Float16* Wtl = (_Float16*)(ws + O_WTL);
  float* partZ = (float*)(ws + OZ);
  float* partF = (float*)(ws + 0);
  _Float16* x1h = (_Float16*)(ws + O_X1H);
  _Float16* x1l = (_Float16*)(ws + O_X1L);
  _Float16* W2th = (_Float16*)(ws + O_W2TH);
  _Float16* W2tl = (_Float16*)(ws + O_W2TL);
  float* partC = (float*)(ws + O_PFC2);
  _Float16* x2h = (_Float16*)(ws + O_X2H);
  _Float16* x2l = (_Float16*)(ws + O_X2L);
  _Float16* whh = (_Float16*)(ws + O_WHH);
  _Float16* whl = (_Float16*)(ws + O_WHL);
  float* bhv   = (float*)(ws + O_BH);
  float* partH = (float*)(ws + O_PARTH);
  float* partH2 = (float*)(ws + O_PARTH + 3ull * 4194304ull);
  float* pbox  = (float*)(ws + O_PBOX);
  unsigned long long* keys = (unsigned long long*)(ws + O_KEYS);
  float* nmsbox = (float*)(ws + O_NMSBOX);
  float* outbox = (float*)(ws + O_OUTBOX);
  float* scorea = (float*)(ws + O_SCORE);
  float* labela = (float*)(ws + O_LABEL);
  unsigned* cnt = (unsigned*)(ws + O_CNT);
  unsigned* maska = (unsigned*)(ws + O_MASK);

  k_transpose<<<dim3(79, 8, 4), 256, 0, stream>>>(features, featT, out);
  k_wsplit<<<dim3(196, 16), 256, 0, stream>>>(W1, Wth, Wtl, 12544, 1024);
  k_roialign<<<2048, 256, 0, stream>>>(featT, proposals, Ahg, Alg);
  // FC1: [2048,12544] x [12544,1024], split-K=4 (z0,z1,z3 @OZ; z2 @featT region)
  k_mfma<<<dim3(8, 16, 4), 256, 0, stream>>>(Ahg, Alg, Wth, Wtl, partZ, partF,
                                             12544, 3136, 1024, 2048 * 1024);
  k_reduce_split<<<1024, 256, 0, stream>>>(partZ, partF, b1, x1h, x1l, 4);
  k_prep2<<<768, 256, 0, stream>>>(W2, Wc, Wr, bc, br, W2th, W2tl, whh, whl, bhv,
                                   (unsigned*)keys, cnt);
  // FC2: [2048,1024] x [1024,1024], split-K=2
  k_mfma<<<dim3(8, 16, 2), 256, 0, stream>>>(x1h, x1l, W2th, W2tl, partC, partC,
                                             1024, 512, 1024, 2048 * 1024);
  k_reduce_split<<<1024, 256, 0, stream>>>(partC, partC, b2, x2h, x2l, 2);
  // heads: [2048,1024] x [1024,512], split-K=4
  k_mfma<<<dim3(4, 16, 4), 256, 0, stream>>>(x2h, x2l, whh, whl, partH, partH2,
                                             1024, 256, 512, 2048 * 512);
  k_softmax_decode<<<512, 256, 0, stream>>>(partH, bhv, proposals, pbox, keys, cnt);
  k_sort<<<4, 1024, 65536, stream>>>(keys, cnt);
  k_gather<<<32, 256, 0, stream>>>(keys, cnt, pbox, (float4*)nmsbox, (float4*)outbox,
                                   scorea, labela);
  k_mask<<<2048, 256, 0, stream>>>(nmsbox, maska);
  k_scan<<<4, 64, 0, stream>>>(maska, cnt, outbox, scorea, labela, out);
}